// Round 15
// baseline (214.692 us; speedup 1.0000x reference)
//
#include <hip/hip_runtime.h>
#include <hip/hip_bf16.h>

// ContrastiveLoss: loss = ( sum_{same & sim<1} (1-sim) + sum_{diff & sim>0.5} sim ) / n
// sim = E E^T, n=8192, d=512. int8 MFMA (mfma_i32_16x16x64_i8), exact i32
// accumulation, quant scale 24, dequant 1/576.
// R15 = R11 with two fixes:
//  (a) correct derived vmcnt: per-thread 4 glls/window; steady-state
//      outstanding = newest 4 only. R11's vmcnt(3) forced a full L2 round
//      trip per window; vmcnt(4) ("all but newest 4 done") is the exact
//      invariant (tile p's glls complete) at zero steady-state cost.
//      p=NPH-1 uses vmcnt(0).
//  (b) ONE barrier per window: {vmcnt; barrier; stage p+2; ds_read p;
//      lgkmcnt(0); sched_barrier; setprio(1) 16 MFMA setprio(0)}.
//      WAR safe: reads of the buffer stage() overwrites retired at the
//      reader's own lgkmcnt(0) last window, before this barrier.
//  Plus: reduction fused into loss_kernel via last-block ticket
//  (threadfence + device-scope atomicAdd; fixed-order sum -> deterministic);
//  ticket zeroed each launch by hipMemsetAsync (graph-capturable).

typedef int   i32x4 __attribute__((ext_vector_type(4)));

#define N_EMB 8192
#define D_EMB 512
#define BM    128
#define HKB   64                 // K-bytes per window (one i8-MFMA K)
#define NPH   (D_EMB / HKB)      // 8 windows
#define TILES (N_EMB / BM)       // 64
#define NBLK  (TILES * (TILES + 1) / 2)   // 2080
#define MARGIN_F 0.5f
#define QSCALE 24.0f
#define DEQ    (1.0f / (QSCALE * QSCALE))  // 1/576
#define HBYT  (BM * HKB)         // 8192 B per operand half-buffer

__device__ __forceinline__ void gll16(const void* g, void* l) {
    __builtin_amdgcn_global_load_lds(
        (const __attribute__((address_space(1))) void*)g,
        (__attribute__((address_space(3))) void*)l,
        16 /*bytes*/, 0 /*offset*/, 0 /*aux*/);
}

// fp32 -> int8 (scale 24, clamp +-127). 16 floats -> 16 bytes per thread.
__global__ __launch_bounds__(256) void quant_kernel(const float* __restrict__ in,
                                                    int4* __restrict__ out, int n16) {
    int i = blockIdx.x * blockDim.x + threadIdx.x;
    if (i >= n16) return;
    const float4* p = reinterpret_cast<const float4*>(in) + i * 4;
    int4 o;
    int* po = reinterpret_cast<int*>(&o);
#pragma unroll
    for (int j = 0; j < 4; ++j) {
        float4 v = p[j];
        int b0 = (int)rintf(fminf(fmaxf(v.x * QSCALE, -127.f), 127.f));
        int b1 = (int)rintf(fminf(fmaxf(v.y * QSCALE, -127.f), 127.f));
        int b2 = (int)rintf(fminf(fmaxf(v.z * QSCALE, -127.f), 127.f));
        int b3 = (int)rintf(fminf(fmaxf(v.w * QSCALE, -127.f), 127.f));
        po[j] = (b0 & 255) | ((b1 & 255) << 8) | ((b2 & 255) << 16) | ((b3 & 255) << 24);
    }
    out[i] = o;
}

__global__ __launch_bounds__(256) void loss_kernel(const char* __restrict__ E8,
                                                   const int* __restrict__ label,
                                                   float* __restrict__ partials,
                                                   int* __restrict__ ticket,
                                                   float* __restrict__ out) {
    // T1: XCD-contiguous logical tile index (2080 % 8 == 0)
    const int bid = blockIdx.x;
    const int t = (bid & 7) * (NBLK / 8) + (bid >> 3);

    // triangular decode: t -> (tr, tc), tr <= tc (validated R2..R12)
    int tr = (int)(64.5f - sqrtf(4160.25f - 2.0f * (float)t));
    while ((tr + 1) * TILES - ((tr + 1) * tr) / 2 <= t) ++tr;
    while (tr * TILES - (tr * (tr - 1)) / 2 > t) --tr;
    const int tc = tr + (t - (tr * TILES - (tr * (tr - 1)) / 2));

    __shared__ char  lds[3][2][HBYT];   // ring-3: [A 8KB | B 8KB] x 3 = 48 KB
    __shared__ float red[4];
    __shared__ int   amLast;

    const int tid  = threadIdx.x;
    const int wid  = tid >> 6, lane = tid & 63;
    const int wrow = wid >> 1, wcol = wid & 1;   // 2x2 waves, each 64x64 out
    const int fr   = lane & 15;                  // fragment row(A)/row(B)/col(C)
    const int kq   = lane >> 4;                  // k-16B-chunk 0..3
    const int row0 = tr * BM, col0 = tc * BM;

    // staging: per half = 128 rows x 64 B = 512 x 16B slots; thread covers
    // slots tid and tid+256. Phys chunk c of row r holds LOGICAL chunk
    // c ^ (r&3): inverse swizzle on global source, lane-linear LDS dest.
    const int sw = (((tid & 3) ^ ((tid >> 2) & 3)) << 4);
    const int r0 = tid >> 2, r1 = 64 + (tid >> 2);
    const char* gA0 = E8 + (size_t)(row0 + r0) * D_EMB + sw;
    const char* gA1 = E8 + (size_t)(row0 + r1) * D_EMB + sw;
    const char* gB0 = E8 + (size_t)(col0 + r0) * D_EMB + sw;
    const char* gB1 = E8 + (size_t)(col0 + r1) * D_EMB + sw;
    const int d0 = tid << 4;
    const int d1 = (tid + 256) << 4;

    i32x4 acc[4][4] = {};

    // ds_read phys chunk: kq ^ (row&3); row&3 == fr&3 for all fragment rows.
    const int psw = ((kq ^ (fr & 3)) << 4);

    // prologue: stage halves 0 and 1 (8 glls outstanding)
    gll16(gA0,       &lds[0][0][d0]); gll16(gA1,       &lds[0][0][d1]);
    gll16(gB0,       &lds[0][1][d0]); gll16(gB1,       &lds[0][1][d1]);
    gll16(gA0 + HKB, &lds[1][0][d0]); gll16(gA1 + HKB, &lds[1][0][d1]);
    gll16(gB0 + HKB, &lds[1][1][d0]); gll16(gB1 + HKB, &lds[1][1][d1]);

#pragma unroll
    for (int p = 0; p < NPH; ++p) {
        const int rg = p % 3;
        // (a) derived wait: all glls except the newest 4 are done = tile p
        //     landed; tile p+1's 4 stay in flight. Zero-cost steady state.
        if (p < NPH - 1) {
            asm volatile("s_waitcnt vmcnt(4)" ::: "memory");
        } else {
            asm volatile("s_waitcnt vmcnt(0)" ::: "memory");
        }
        __builtin_amdgcn_s_barrier();   // publish tile p; buf (p+2)%3 free

        // (b) stage p+2 (its last readers finished before this barrier)
        if (p + 2 < NPH) {
            const int rg2 = (p + 2) % 3;
            const int ko  = (p + 2) * HKB;
            gll16(gA0 + ko, &lds[rg2][0][d0]); gll16(gA1 + ko, &lds[rg2][0][d1]);
            gll16(gB0 + ko, &lds[rg2][1][d0]); gll16(gB1 + ko, &lds[rg2][1][d1]);
        }

        // read this window's fragments and MFMA
        i32x4 a[4], b[4];
#pragma unroll
        for (int m = 0; m < 4; ++m)
            a[m] = *reinterpret_cast<const i32x4*>(
                &lds[rg][0][((wrow * 64 + m * 16 + fr) << 6) + psw]);
#pragma unroll
        for (int n = 0; n < 4; ++n)
            b[n] = *reinterpret_cast<const i32x4*>(
                &lds[rg][1][((wcol * 64 + n * 16 + fr) << 6) + psw]);
        asm volatile("s_waitcnt lgkmcnt(0)" ::: "memory");
        __builtin_amdgcn_sched_barrier(0);   // rule #18
        __builtin_amdgcn_s_setprio(1);
#pragma unroll
        for (int m = 0; m < 4; ++m)
#pragma unroll
            for (int n = 0; n < 4; ++n)
                acc[m][n] = __builtin_amdgcn_mfma_i32_16x16x64_i8(a[m], b[n], acc[m][n], 0, 0, 0);
        __builtin_amdgcn_s_setprio(0);
    }

    // ---- epilogue: C/D layout col = lane&15, row = (lane>>4)*4 + reg.
    float local = 0.f;
    int lj[4];
#pragma unroll
    for (int n = 0; n < 4; ++n) lj[n] = label[col0 + wcol * 64 + n * 16 + fr];
    const int rb = kq << 2;
#pragma unroll
    for (int m = 0; m < 4; ++m) {
#pragma unroll
        for (int r = 0; r < 4; ++r) {
            const int li = label[row0 + wrow * 64 + m * 16 + rb + r];
#pragma unroll
            for (int n = 0; n < 4; ++n) {
                const float s = (float)acc[m][n][r] * DEQ;
                if (li == lj[n]) {
                    if (s < 1.0f) local += 1.0f - s;
                } else if (s > MARGIN_F) {
                    local += s;
                }
            }
        }
    }
    if (tr != tc) local *= 2.0f;   // off-diag tile stands for (i,j) and (j,i)

#pragma unroll
    for (int off = 32; off > 0; off >>= 1) local += __shfl_xor(local, off);
    if (lane == 0) red[wid] = local;
    __syncthreads();
    if (tid == 0) partials[t] = red[0] + red[1] + red[2] + red[3];

    // ---- fused final reduction: last block sums in fixed order ----
    __threadfence();                       // make partials[t] device-visible
    if (tid == 0) amLast = (atomicAdd(ticket, 1) == NBLK - 1);
    __syncthreads();
    if (amLast) {
        __threadfence();                   // acquire all partials
        float s = 0.f;
        for (int i = tid; i < NBLK; i += 256) s += partials[i];
#pragma unroll
        for (int off = 32; off > 0; off >>= 1) s += __shfl_xor(s, off);
        if (lane == 0) red[wid] = s;
        __syncthreads();
        if (tid == 0) {
            out[0] = (red[0] + red[1] + red[2] + red[3]) * (1.0f / (float)N_EMB);
            out[1] = 0.f;
            out[2] = 0.f;
        }
    }
}

extern "C" void kernel_launch(void* const* d_in, const int* in_sizes, int n_in,
                              void* d_out, int out_size, void* d_ws, size_t ws_size,
                              hipStream_t stream) {
    const float* emb   = (const float*)d_in[0];
    const int*   label = (const int*)d_in[1];
    float*       out   = (float*)d_out;

    char*  E8      = (char*)d_ws;                                   // 4 MB
    float* partial = (float*)((char*)d_ws + (size_t)N_EMB * D_EMB); // 8.3 KB
    int*   ticket  = (int*)((char*)d_ws + (size_t)N_EMB * D_EMB + NBLK * sizeof(float));

    hipMemsetAsync(ticket, 0, sizeof(int), stream);   // reset per launch

    const int n16 = N_EMB * D_EMB / 16;
    quant_kernel<<<(n16 + 255) / 256, 256, 0, stream>>>(emb, (int4*)E8, n16);

    loss_kernel<<<NBLK, 256, 0, stream>>>(E8, label, partial, ticket, out);
}

// Round 16
// 46.394 us; speedup vs baseline: 4.6276x; 4.6276x over previous
//
#include <hip/hip_runtime.h>
#include <hip/hip_bf16.h>

// ContrastiveLoss: loss = ( sum_{same & sim<1} (1-sim) + sum_{diff & sim>0.5} sim ) / n
// sim = E E^T, n=8192, d=512. int8 MFMA (mfma_i32_16x16x64_i8), exact i32
// accumulation, quant scale 24, dequant 1/576.
// R16 = R11 + (a) correct derived vmcnt + (b) one barrier per window,
// WITHOUT R15's fused reduction (its agent-scope __threadfence forced L2
// writeback/invalidate per block on multi-XCD gfx950 -> evicted the
// L2-resident input under every in-flight block -> 204us latency collapse;
// FETCH unchanged because L3 absorbed the misses).
//  (a) per-thread 4 glls/window; steady-state outstanding = newest 4 only.
//      vmcnt(4) = "all but newest 4 done" = tile p landed, tile p+1 in
//      flight, zero steady-state stall. p=NPH-1 uses vmcnt(0).
//  (b) window = {vmcnt; barrier; stage p+2; 8 ds_read; lgkmcnt(0);
//      sched_barrier; setprio(1) 16 MFMA setprio(0)}. WAR safe: reads of the
//      buffer stage() overwrites retired at the reader's own lgkmcnt(0) in
//      window p-1, which precedes this window's barrier in program order.
// Separate reduce_kernel (fixed-order, deterministic). Quant/swizzle/decode/
// epilogue/T1 identical to validated R9/R11.

typedef int   i32x4 __attribute__((ext_vector_type(4)));

#define N_EMB 8192
#define D_EMB 512
#define BM    128
#define HKB   64                 // K-bytes per window (one i8-MFMA K)
#define NPH   (D_EMB / HKB)      // 8 windows
#define TILES (N_EMB / BM)       // 64
#define NBLK  (TILES * (TILES + 1) / 2)   // 2080
#define MARGIN_F 0.5f
#define QSCALE 24.0f
#define DEQ    (1.0f / (QSCALE * QSCALE))  // 1/576
#define HBYT  (BM * HKB)         // 8192 B per operand half-buffer

__device__ __forceinline__ void gll16(const void* g, void* l) {
    __builtin_amdgcn_global_load_lds(
        (const __attribute__((address_space(1))) void*)g,
        (__attribute__((address_space(3))) void*)l,
        16 /*bytes*/, 0 /*offset*/, 0 /*aux*/);
}

// fp32 -> int8 (scale 24, clamp +-127). 16 floats -> 16 bytes per thread.
__global__ __launch_bounds__(256) void quant_kernel(const float* __restrict__ in,
                                                    int4* __restrict__ out, int n16) {
    int i = blockIdx.x * blockDim.x + threadIdx.x;
    if (i >= n16) return;
    const float4* p = reinterpret_cast<const float4*>(in) + i * 4;
    int4 o;
    int* po = reinterpret_cast<int*>(&o);
#pragma unroll
    for (int j = 0; j < 4; ++j) {
        float4 v = p[j];
        int b0 = (int)rintf(fminf(fmaxf(v.x * QSCALE, -127.f), 127.f));
        int b1 = (int)rintf(fminf(fmaxf(v.y * QSCALE, -127.f), 127.f));
        int b2 = (int)rintf(fminf(fmaxf(v.z * QSCALE, -127.f), 127.f));
        int b3 = (int)rintf(fminf(fmaxf(v.w * QSCALE, -127.f), 127.f));
        po[j] = (b0 & 255) | ((b1 & 255) << 8) | ((b2 & 255) << 16) | ((b3 & 255) << 24);
    }
    out[i] = o;
}

__global__ __launch_bounds__(256) void loss_kernel(const char* __restrict__ E8,
                                                   const int* __restrict__ label,
                                                   float* __restrict__ partials) {
    // T1: XCD-contiguous logical tile index (2080 % 8 == 0)
    const int bid = blockIdx.x;
    const int t = (bid & 7) * (NBLK / 8) + (bid >> 3);

    // triangular decode: t -> (tr, tc), tr <= tc (validated R2..R12)
    int tr = (int)(64.5f - sqrtf(4160.25f - 2.0f * (float)t));
    while ((tr + 1) * TILES - ((tr + 1) * tr) / 2 <= t) ++tr;
    while (tr * TILES - (tr * (tr - 1)) / 2 > t) --tr;
    const int tc = tr + (t - (tr * TILES - (tr * (tr - 1)) / 2));

    __shared__ char  lds[3][2][HBYT];   // ring-3: [A 8KB | B 8KB] x 3 = 48 KB
    __shared__ float red[4];

    const int tid  = threadIdx.x;
    const int wid  = tid >> 6, lane = tid & 63;
    const int wrow = wid >> 1, wcol = wid & 1;   // 2x2 waves, each 64x64 out
    const int fr   = lane & 15;                  // fragment row(A)/row(B)/col(C)
    const int kq   = lane >> 4;                  // k-16B-chunk 0..3
    const int row0 = tr * BM, col0 = tc * BM;

    // staging: per half = 128 rows x 64 B = 512 x 16B slots; thread covers
    // slots tid and tid+256. Phys chunk c of row r holds LOGICAL chunk
    // c ^ (r&3): inverse swizzle on global source, lane-linear LDS dest.
    const int sw = (((tid & 3) ^ ((tid >> 2) & 3)) << 4);
    const int r0 = tid >> 2, r1 = 64 + (tid >> 2);
    const char* gA0 = E8 + (size_t)(row0 + r0) * D_EMB + sw;
    const char* gA1 = E8 + (size_t)(row0 + r1) * D_EMB + sw;
    const char* gB0 = E8 + (size_t)(col0 + r0) * D_EMB + sw;
    const char* gB1 = E8 + (size_t)(col0 + r1) * D_EMB + sw;
    const int d0 = tid << 4;
    const int d1 = (tid + 256) << 4;

    i32x4 acc[4][4] = {};

    // ds_read phys chunk: kq ^ (row&3); row&3 == fr&3 for all fragment rows.
    const int psw = ((kq ^ (fr & 3)) << 4);

    // prologue: stage halves 0 and 1 (8 glls outstanding)
    gll16(gA0,       &lds[0][0][d0]); gll16(gA1,       &lds[0][0][d1]);
    gll16(gB0,       &lds[0][1][d0]); gll16(gB1,       &lds[0][1][d1]);
    gll16(gA0 + HKB, &lds[1][0][d0]); gll16(gA1 + HKB, &lds[1][0][d1]);
    gll16(gB0 + HKB, &lds[1][1][d0]); gll16(gB1 + HKB, &lds[1][1][d1]);

#pragma unroll
    for (int p = 0; p < NPH; ++p) {
        const int rg = p % 3;
        // (a) derived wait: all but the newest 4 done = tile p landed.
        if (p < NPH - 1) {
            asm volatile("s_waitcnt vmcnt(4)" ::: "memory");
        } else {
            asm volatile("s_waitcnt vmcnt(0)" ::: "memory");
        }
        __builtin_amdgcn_s_barrier();   // publish tile p; buf (p+2)%3 free

        // (b) stage p+2 (last readers retired before this barrier)
        if (p + 2 < NPH) {
            const int rg2 = (p + 2) % 3;
            const int ko  = (p + 2) * HKB;
            gll16(gA0 + ko, &lds[rg2][0][d0]); gll16(gA1 + ko, &lds[rg2][0][d1]);
            gll16(gB0 + ko, &lds[rg2][1][d0]); gll16(gB1 + ko, &lds[rg2][1][d1]);
        }

        // read this window's fragments and MFMA
        i32x4 a[4], b[4];
#pragma unroll
        for (int m = 0; m < 4; ++m)
            a[m] = *reinterpret_cast<const i32x4*>(
                &lds[rg][0][((wrow * 64 + m * 16 + fr) << 6) + psw]);
#pragma unroll
        for (int n = 0; n < 4; ++n)
            b[n] = *reinterpret_cast<const i32x4*>(
                &lds[rg][1][((wcol * 64 + n * 16 + fr) << 6) + psw]);
        asm volatile("s_waitcnt lgkmcnt(0)" ::: "memory");
        __builtin_amdgcn_sched_barrier(0);   // rule #18
        __builtin_amdgcn_s_setprio(1);
#pragma unroll
        for (int m = 0; m < 4; ++m)
#pragma unroll
            for (int n = 0; n < 4; ++n)
                acc[m][n] = __builtin_amdgcn_mfma_i32_16x16x64_i8(a[m], b[n], acc[m][n], 0, 0, 0);
        __builtin_amdgcn_s_setprio(0);
    }

    // ---- epilogue: C/D layout col = lane&15, row = (lane>>4)*4 + reg.
    float local = 0.f;
    int lj[4];
#pragma unroll
    for (int n = 0; n < 4; ++n) lj[n] = label[col0 + wcol * 64 + n * 16 + fr];
    const int rb = kq << 2;
#pragma unroll
    for (int m = 0; m < 4; ++m) {
#pragma unroll
        for (int r = 0; r < 4; ++r) {
            const int li = label[row0 + wrow * 64 + m * 16 + rb + r];
#pragma unroll
            for (int n = 0; n < 4; ++n) {
                const float s = (float)acc[m][n][r] * DEQ;
                if (li == lj[n]) {
                    if (s < 1.0f) local += 1.0f - s;
                } else if (s > MARGIN_F) {
                    local += s;
                }
            }
        }
    }
    if (tr != tc) local *= 2.0f;   // off-diag tile stands for (i,j) and (j,i)

#pragma unroll
    for (int off = 32; off > 0; off >>= 1) local += __shfl_xor(local, off);
    if (lane == 0) red[wid] = local;
    __syncthreads();
    if (tid == 0) partials[t] = red[0] + red[1] + red[2] + red[3];
}

__global__ __launch_bounds__(256) void reduce_kernel(const float* __restrict__ partials,
                                                     float* __restrict__ out, int nb) {
    float s = 0.f;
    for (int i = threadIdx.x; i < nb; i += 256) s += partials[i];
#pragma unroll
    for (int off = 32; off > 0; off >>= 1) s += __shfl_xor(s, off);
    __shared__ float red[4];
    if ((threadIdx.x & 63) == 0) red[threadIdx.x >> 6] = s;
    __syncthreads();
    if (threadIdx.x == 0) {
        out[0] = (red[0] + red[1] + red[2] + red[3]) * (1.0f / (float)N_EMB);
        out[1] = 0.f;
        out[2] = 0.f;
    }
}

extern "C" void kernel_launch(void* const* d_in, const int* in_sizes, int n_in,
                              void* d_out, int out_size, void* d_ws, size_t ws_size,
                              hipStream_t stream) {
    const float* emb   = (const float*)d_in[0];
    const int*   label = (const int*)d_in[1];
    float*       out   = (float*)d_out;

    char*  E8      = (char*)d_ws;                                   // 4 MB
    float* partial = (float*)((char*)d_ws + (size_t)N_EMB * D_EMB); // 8.3 KB

    const int n16 = N_EMB * D_EMB / 16;
    quant_kernel<<<(n16 + 255) / 256, 256, 0, stream>>>(emb, (int4*)E8, n16);

    loss_kernel<<<NBLK, 256, 0, stream>>>(E8, label, partial);

    reduce_kernel<<<1, 256, 0, stream>>>(partial, out, NBLK);
}